// Round 5
// baseline (210.662 us; speedup 1.0000x reference)
//
#include <hip/hip_runtime.h>
#include <hip/hip_bf16.h>

typedef __attribute__((ext_vector_type(4))) float f32x4;
typedef __attribute__((ext_vector_type(16))) float f32x16;
typedef __attribute__((ext_vector_type(8))) short short8;

static constexpr int Ssz = 2048;
static constexpr int Dsz = 1024;

__device__ __forceinline__ unsigned short f2bf(float f){
  union { float f; unsigned u; } c; c.f = f;
  unsigned r = c.u + 0x7fffu + ((c.u >> 16) & 1u);
  return (unsigned short)(r >> 16);
}

__device__ __forceinline__ void gl2lds16(const void* g, void* l){
  __builtin_amdgcn_global_load_lds(
    (const __attribute__((address_space(1))) unsigned int*)g,
    (__attribute__((address_space(3))) unsigned int*)l, 16, 0, 0);
}

__device__ __forceinline__ unsigned cvtpk(float lo, float hi){
  unsigned r;
  asm("v_cvt_pk_bf16_f32 %0, %1, %2" : "=v"(r) : "v"(lo), "v"(hi));
  return r;
}

__device__ __forceinline__ void permswap(unsigned &a, unsigned &b){
  asm volatile("v_permlane32_swap_b32 %0, %1" : "+v"(a), "+v"(b));
}

__device__ __forceinline__ float xmax64(float x){
  float a = x, b;
  asm volatile("v_mov_b32 %0, %1" : "=v"(b) : "v"(a));
  asm volatile("v_permlane32_swap_b32 %0, %1" : "+v"(a), "+v"(b));
  return fmaxf(a, b);
}
__device__ __forceinline__ float xsum64(float x){
  float a = x, b;
  asm volatile("v_mov_b32 %0, %1" : "=v"(b) : "v"(a));
  asm volatile("v_permlane32_swap_b32 %0, %1" : "+v"(a), "+v"(b));
  return a + b;
}

// ---------------- fp32 -> bf16 elementwise (8/thread) ----------------
__global__ void cvt_kernel(const float* __restrict__ in, unsigned short* __restrict__ out, int n){
  int i = (blockIdx.x * 256 + threadIdx.x) * 8;
  if (i >= n) return;
  float4 a = *(const float4*)(in + i);
  float4 b = *(const float4*)(in + i + 4);
  short8 o;
  o[0]=(short)f2bf(a.x); o[1]=(short)f2bf(a.y); o[2]=(short)f2bf(a.z); o[3]=(short)f2bf(a.w);
  o[4]=(short)f2bf(b.x); o[5]=(short)f2bf(b.y); o[6]=(short)f2bf(b.z); o[7]=(short)f2bf(b.w);
  *(short8*)(out + i) = o;
}

// ---------------- fp32 [R][C] -> bf16 [C][R] transpose ----------------
__global__ void transpose_kernel(const float* __restrict__ in, unsigned short* __restrict__ out,
                                 int R, int C){
  __shared__ float tile[32][33];
  int c0 = blockIdx.x * 32, r0 = blockIdx.y * 32;
  int tx = threadIdx.x, ty = threadIdx.y;
  #pragma unroll
  for (int k = 0; k < 4; ++k)
    tile[ty + 8*k][tx] = in[(size_t)(r0 + ty + 8*k) * C + c0 + tx];
  __syncthreads();
  #pragma unroll
  for (int k = 0; k < 4; ++k)
    out[(size_t)(c0 + ty + 8*k) * R + r0 + tx] = f2bf(tile[tx][ty + 8*k]);
}

// ============ QKV GEMM: 256x256, BK=64, 4-phase/K-tile, single vmcnt/tile ============
// Stage lead ~7 half-tiles: during tile t phases stage (t+1)B-hi, (t+2)B-lo, (t+2)A-lo,
// (t+2)A-hi. Tile tau's halves are global h(4tau..4tau+3); vmcnt(6) at end of tile t
// proves completion through h(4t+7) = ALL of tile t+1. A-lo held in regs P1..P4 so each
// LDS region is read in exactly one phase => 2-tile-ahead stages are barrier-safe.
__global__ __launch_bounds__(512, 2)
void gemm_qkv(const unsigned short* __restrict__ A, const unsigned short* __restrict__ Bt,
              const float* __restrict__ bias,
              unsigned short* __restrict__ Qp, unsigned short* __restrict__ Kp,
              unsigned short* __restrict__ Vtp)
{
  constexpr int K = 1024, NT = 16;
  __shared__ unsigned short ldsA[2][256 * 64];
  __shared__ unsigned short ldsB[2][256 * 64];
  const int tid = threadIdx.x;
  const int wid = tid >> 6, lane = tid & 63;
  const int lr = lane & 15, lg = lane >> 4;
  const int wm = wid >> 2, wn = wid & 3;

  int bid = blockIdx.x;
  int swz = (bid & 7) * 48 + (bid >> 3);
  const int m0 = (swz / 12) * 256, n0 = (swz % 12) * 256;

  const f32x4 vzero = {0.f, 0.f, 0.f, 0.f};
  f32x4 acc[8][4];
  #pragma unroll
  for (int i = 0; i < 8; ++i)
    #pragma unroll
    for (int j = 0; j < 4; ++j) acc[i][j] = vzero;

  // one half-tile (16KB, 2 loads/thread). op: 0=B-lo 1=A-lo 2=A-hi 3=B-hi
  auto stage = [&](int ts, int op){
    if (ts >= NT) return;
    const int buf = ts & 1;
    #pragma unroll
    for (int call = 0; call < 2; ++call){
      int c = call * 512 + tid;
      int rw = c >> 3, cc = c & 7;
      if (op == 0 || op == 3){
        int row = ((rw >> 5) << 6) + (rw & 31) + (op == 3 ? 32 : 0);
        int sc = cc ^ (row & 7);
        gl2lds16(Bt + (size_t)(n0 + row) * K + ts * 64 + sc * 8,
                 &ldsB[buf][row * 64 + cc * 8]);
      } else {
        int row = ((rw >> 6) << 7) + (rw & 63) + (op == 2 ? 64 : 0);
        int sc = cc ^ (row & 7);
        gl2lds16(A + (size_t)(m0 + row) * K + ts * 64 + sc * 8,
                 &ldsA[buf][row * 64 + cc * 8]);
      }
    }
  };

  short8 af_lo[4][2], af_hi[4][2], bfr[2][2];

  // prologue: tile0 all 4 halves + tile1 halves 0-2 (= h0..h6, 14 loads);
  // vmcnt(6) -> h0..h3 complete (tile 0 ready)
  stage(0, 0); stage(0, 1); stage(0, 2); stage(0, 3);
  stage(1, 0); stage(1, 1); stage(1, 2);
  asm volatile("s_waitcnt vmcnt(6)" ::: "memory");
  __builtin_amdgcn_sched_barrier(0);
  __builtin_amdgcn_s_barrier();

  #pragma unroll 1
  for (int t = 0; t < NT; ++t){
    const char* baA = (const char*)&ldsA[t & 1][0];
    const char* baB = (const char*)&ldsB[t & 1][0];

    // ---- P1: quadrant (0,0); read A-lo (held through P4) + B-lo ----
    #pragma unroll
    for (int ii = 0; ii < 4; ++ii)
      #pragma unroll
      for (int kk = 0; kk < 2; ++kk){
        int row = wm * 128 + ii * 16 + lr;
        int off = (row * 128 + lg * 16 + kk * 64) ^ ((row & 7) << 4);
        af_lo[ii][kk] = *(const short8*)(baA + off);
      }
    #pragma unroll
    for (int jj = 0; jj < 2; ++jj)
      #pragma unroll
      for (int kk = 0; kk < 2; ++kk){
        int row = wn * 64 + jj * 16 + lr;
        int off = (row * 128 + lg * 16 + kk * 64) ^ ((row & 7) << 4);
        bfr[jj][kk] = *(const short8*)(baB + off);
      }
    stage(t + 1, 3);
    __builtin_amdgcn_s_barrier();
    asm volatile("s_waitcnt lgkmcnt(0)" ::: "memory");
    __builtin_amdgcn_sched_barrier(0);
    __builtin_amdgcn_s_setprio(1);
    #pragma unroll
    for (int ii = 0; ii < 4; ++ii)
      #pragma unroll
      for (int jj = 0; jj < 2; ++jj)
        #pragma unroll
        for (int kk = 0; kk < 2; ++kk)
          acc[ii][jj] = __builtin_amdgcn_mfma_f32_16x16x32_bf16(af_lo[ii][kk], bfr[jj][kk], acc[ii][jj], 0, 0, 0);
    __builtin_amdgcn_s_setprio(0);
    __builtin_amdgcn_s_barrier();

    // ---- P2: quadrant (1,0); read A-hi, reuse B-lo ----
    #pragma unroll
    for (int ii = 0; ii < 4; ++ii)
      #pragma unroll
      for (int kk = 0; kk < 2; ++kk){
        int row = wm * 128 + 64 + ii * 16 + lr;
        int off = (row * 128 + lg * 16 + kk * 64) ^ ((row & 7) << 4);
        af_hi[ii][kk] = *(const short8*)(baA + off);
      }
    stage(t + 2, 0);
    __builtin_amdgcn_s_barrier();
    asm volatile("s_waitcnt lgkmcnt(0)" ::: "memory");
    __builtin_amdgcn_sched_barrier(0);
    __builtin_amdgcn_s_setprio(1);
    #pragma unroll
    for (int ii = 0; ii < 4; ++ii)
      #pragma unroll
      for (int jj = 0; jj < 2; ++jj)
        #pragma unroll
        for (int kk = 0; kk < 2; ++kk)
          acc[4 + ii][jj] = __builtin_amdgcn_mfma_f32_16x16x32_bf16(af_hi[ii][kk], bfr[jj][kk], acc[4 + ii][jj], 0, 0, 0);
    __builtin_amdgcn_s_setprio(0);
    __builtin_amdgcn_s_barrier();

    // ---- P3: quadrant (1,1); read B-hi, reuse A-hi ----
    #pragma unroll
    for (int jj = 0; jj < 2; ++jj)
      #pragma unroll
      for (int kk = 0; kk < 2; ++kk){
        int row = wn * 64 + 32 + jj * 16 + lr;
        int off = (row * 128 + lg * 16 + kk * 64) ^ ((row & 7) << 4);
        bfr[jj][kk] = *(const short8*)(baB + off);
      }
    stage(t + 2, 1);
    __builtin_amdgcn_s_barrier();
    asm volatile("s_waitcnt lgkmcnt(0)" ::: "memory");
    __builtin_amdgcn_sched_barrier(0);
    __builtin_amdgcn_s_setprio(1);
    #pragma unroll
    for (int ii = 0; ii < 4; ++ii)
      #pragma unroll
      for (int jj = 0; jj < 2; ++jj)
        #pragma unroll
        for (int kk = 0; kk < 2; ++kk)
          acc[4 + ii][2 + jj] = __builtin_amdgcn_mfma_f32_16x16x32_bf16(af_hi[ii][kk], bfr[jj][kk], acc[4 + ii][2 + jj], 0, 0, 0);
    __builtin_amdgcn_s_setprio(0);
    __builtin_amdgcn_s_barrier();

    // ---- P4: quadrant (0,1); no ds_read (A-lo regs + B-hi regs) ----
    stage(t + 2, 2);
    __builtin_amdgcn_s_barrier();
    __builtin_amdgcn_s_setprio(1);
    #pragma unroll
    for (int ii = 0; ii < 4; ++ii)
      #pragma unroll
      for (int jj = 0; jj < 2; ++jj)
        #pragma unroll
        for (int kk = 0; kk < 2; ++kk)
          acc[ii][2 + jj] = __builtin_amdgcn_mfma_f32_16x16x32_bf16(af_lo[ii][kk], bfr[jj][kk], acc[ii][2 + jj], 0, 0, 0);
    __builtin_amdgcn_s_setprio(0);
    asm volatile("s_waitcnt vmcnt(6)" ::: "memory");
    __builtin_amdgcn_sched_barrier(0);
    __builtin_amdgcn_s_barrier();
  }

  asm volatile("s_waitcnt vmcnt(0)" ::: "memory");

  // epilogue: bias + scatter to Q (exp2-domain prescale), K, V^T
  const float qscale = 0.125f * 1.4426950408889634f;
  #pragma unroll
  for (int i = 0; i < 8; ++i)
    #pragma unroll
    for (int j = 0; j < 4; ++j)
      #pragma unroll
      for (int r = 0; r < 4; ++r){
        int gm = m0 + wm * 128 + i * 16 + lg * 4 + r;
        int gn = n0 + wn * 64 + j * 16 + lr;
        float v = acc[i][j][r] + bias[gn];
        int which = gn >> 10;
        int h = (gn >> 6) & 15;
        int hd = gn & 63;
        int b = gm >> 11;
        int s = gm & 2047;
        size_t bh = (size_t)(b * 16 + h);
        if (which == 0)      Qp[(bh * Ssz + s) * 64 + hd] = f2bf(v * qscale);
        else if (which == 1) Kp[(bh * Ssz + s) * 64 + hd] = f2bf(v);
        else                 Vtp[(bh * 64 + hd) * Ssz + s] = f2bf(v);
      }
}

// ---------------- bf16 GEMM (out-proj): C[M][N] = A[M][K] * Bt[N][K]^T + bias ----------------
#define BM 128
#define BN 128
#define BKg 64

__global__ __launch_bounds__(256, 2)
void gemm_bt(const unsigned short* __restrict__ A, const unsigned short* __restrict__ Bt,
             int M, int N, int K,
             const float* __restrict__ bias, float* __restrict__ Out)
{
  __shared__ unsigned short ldsA[BM * BKg];
  __shared__ unsigned short ldsB[BN * BKg];
  const int tid = threadIdx.x;
  const int wid = tid >> 6;
  const int lane = tid & 63;
  const int lr = lane & 15, lg = lane >> 4;
  const int wr = wid >> 1, wc = wid & 1;
  const int m0 = blockIdx.y * BM, n0 = blockIdx.x * BN;

  const f32x4 vzero = {0.f, 0.f, 0.f, 0.f};
  f32x4 acc[4][4];
  #pragma unroll
  for (int i = 0; i < 4; ++i)
    #pragma unroll
    for (int j = 0; j < 4; ++j) acc[i][j] = vzero;

  for (int k0 = 0; k0 < K; k0 += BKg){
    __syncthreads();
    #pragma unroll
    for (int it = 0; it < 4; ++it){
      int c = it * 256 + tid;
      int row = c >> 3;
      int sc = (c & 7) ^ (row & 7);
      gl2lds16(A  + (size_t)(m0 + row) * K + k0 + sc * 8,
               (char*)ldsA + (it * 256 + wid * 64) * 16);
      gl2lds16(Bt + (size_t)(n0 + row) * K + k0 + sc * 8,
               (char*)ldsB + (it * 256 + wid * 64) * 16);
    }
    __syncthreads();
    #pragma unroll
    for (int kc = 0; kc < 2; ++kc){
      short8 af[4], bfr[4];
      #pragma unroll
      for (int i = 0; i < 4; ++i){
        int row = wr * 64 + i * 16 + lr;
        int off = row * 128 + lg * 16 + kc * 64;
        off ^= (row & 7) << 4;
        af[i] = *(const short8*)((const char*)ldsA + off);
      }
      #pragma unroll
      for (int j = 0; j < 4; ++j){
        int row = wc * 64 + j * 16 + lr;
        int off = row * 128 + lg * 16 + kc * 64;
        off ^= (row & 7) << 4;
        bfr[j] = *(const short8*)((const char*)ldsB + off);
      }
      #pragma unroll
      for (int i = 0; i < 4; ++i)
        #pragma unroll
        for (int j = 0; j < 4; ++j)
          acc[i][j] = __builtin_amdgcn_mfma_f32_16x16x32_bf16(af[i], bfr[j], acc[i][j], 0, 0, 0);
    }
  }

  #pragma unroll
  for (int i = 0; i < 4; ++i)
    #pragma unroll
    for (int j = 0; j < 4; ++j)
      #pragma unroll
      for (int r = 0; r < 4; ++r){
        int gm = m0 + wr * 64 + i * 16 + lg * 4 + r;
        int gn = n0 + wc * 64 + j * 16 + lr;
        Out[(size_t)gm * N + gn] = acc[i][j][r] + bias[gn];
      }
}

// ---------------- causal flash attention, swapped-QK 32x32, balanced ----------------
__global__ __launch_bounds__(256, 2)
void attn_kernel(const unsigned short* __restrict__ Qp, const unsigned short* __restrict__ Kp,
                 const unsigned short* __restrict__ Vtp, unsigned short* __restrict__ Att)
{
  __shared__ unsigned short ldsK[2][4096];
  __shared__ unsigned short ldsV[2][4096];
  const int tid = threadIdx.x;
  const int wid = tid >> 6;
  const int lane = tid & 63;
  const int lq = lane & 31;
  const int hi = lane >> 5;
  const int bh = blockIdx.y;
  const int b = bh >> 4, hh = bh & 15;

  #pragma unroll 1
  for (int job = 0; job < 2; ++job){
    const int qt = job ? (15 - (int)blockIdx.x) : (int)blockIdx.x;
    const int q0w = qt * 128 + wid * 32;
    const int qa = q0w + lq;
    const int nt = 2 * qt + 2;

    short8 qf[4];
    {
      const unsigned short* Qb = Qp + ((size_t)bh * Ssz + q0w + lq) * 64 + hi * 8;
      #pragma unroll
      for (int ks = 0; ks < 4; ++ks) qf[ks] = *(const short8*)(Qb + ks * 16);
    }

    f32x16 Ot[2];
    #pragma unroll
    for (int d = 0; d < 2; ++d)
      #pragma unroll
      for (int r = 0; r < 16; ++r) Ot[d][r] = 0.f;
    float mrun = -3e38f, lsum = 0.f;

    #pragma unroll
    for (int it = 0; it < 2; ++it){
      int c = it * 256 + tid;
      int row = c >> 3, sc = (c & 7) ^ (row & 7);
      gl2lds16(Kp  + ((size_t)bh * Ssz + row) * 64 + sc * 8,
               (char*)&ldsK[0][0] + (it * 256 + wid * 64) * 16);
      gl2lds16(Vtp + ((size_t)bh * 64 + row) * Ssz + sc * 8,
               (char*)&ldsV[0][0] + (it * 256 + wid * 64) * 16);
    }
    __syncthreads();

    for (int kt = 0; kt < nt; ++kt){
      const int cur = kt & 1;
      if (kt + 1 < nt){
        const int nxt = cur ^ 1;
        #pragma unroll
        for (int it = 0; it < 2; ++it){
          int c = it * 256 + tid;
          int row = c >> 3, sc = (c & 7) ^ (row & 7);
          gl2lds16(Kp  + ((size_t)bh * Ssz + (kt + 1) * 64 + row) * 64 + sc * 8,
                   (char*)&ldsK[nxt][0] + (it * 256 + wid * 64) * 16);
          gl2lds16(Vtp + ((size_t)bh * 64 + row) * Ssz + (kt + 1) * 64 + sc * 8,
                   (char*)&ldsV[nxt][0] + (it * 256 + wid * 64) * 16);
        }
      }

      if (kt * 64 <= q0w + 31){
        const char* Kb = (const char*)&ldsK[cur][0];
        const char* Vb = (const char*)&ldsV[cur][0];

        f32x16 S[2];
        #pragma unroll
        for (int kb = 0; kb < 2; ++kb)
          #pragma unroll
          for (int r = 0; r < 16; ++r) S[kb][r] = 0.f;
        #pragma unroll
        for (int ks = 0; ks < 4; ++ks){
          int col = 32 * ks + 16 * hi;
          int r0 = lq, r1 = 32 + lq;
          short8 k0 = *(const short8*)(Kb + ((r0 * 128 + col) ^ ((r0 & 7) << 4)));
          short8 k1 = *(const short8*)(Kb + ((r1 * 128 + col) ^ ((r1 & 7) << 4)));
          S[0] = __builtin_amdgcn_mfma_f32_32x32x16_bf16(k0, qf[ks], S[0], 0, 0, 0);
          S[1] = __builtin_amdgcn_mfma_f32_32x32x16_bf16(k1, qf[ks], S[1], 0, 0, 0);
        }

        if (kt * 64 + 63 > q0w){
          #pragma unroll
          for (int r = 0; r < 16; ++r){
            int keyb = kt * 64 + (r & 3) + ((r >> 2) << 3) + 4 * hi;
            if (keyb > qa)      S[0][r] = -3e38f;
            if (keyb + 32 > qa) S[1][r] = -3e38f;
          }
        }

        float t16[16];
        #pragma unroll
        for (int r = 0; r < 16; ++r) t16[r] = fmaxf(S[0][r], S[1][r]);
        float t8[8];
        #pragma unroll
        for (int r = 0; r < 8; ++r) t8[r] = fmaxf(t16[r], t16[r + 8]);
        float t4[4];
        #pragma unroll
        for (int r = 0; r < 4; ++r) t4[r] = fmaxf(t8[r], t8[r + 4]);
        float pmax = fmaxf(fmaxf(t4[0], t4[1]), fmaxf(t4[2], t4[3]));
        pmax = xmax64(pmax);

        if (!__all(pmax - mrun <= 8.0f)){
          float mn = fmaxf(mrun, pmax);
          float scl = __builtin_amdgcn_exp2f(mrun - mn);
          mrun = mn;
          lsum *= scl;
          #pragma unroll
          for (int d = 0; d < 2; ++d)
            #pragma unroll
            for (int r = 0; r < 16; ++r) Ot[d][r] *= scl;
        }

        #pragma unroll
        for (int kb = 0; kb < 2; ++kb)
          #pragma unroll
          for (int r = 0; r < 16; ++r)
            S[kb][r] = __builtin_amdgcn_exp2f(S[kb][r] - mrun);

        #pragma unroll
        for (int r = 0; r < 16; ++r) t16[r] = S[0][r] + S[1][r];
        #pragma unroll
        for (int r = 0; r < 8; ++r) t8[r] = t16[r] + t16[r + 8];
        #pragma unroll
        for (int r = 0; r < 4; ++r) t4[r] = t8[r] + t8[r + 4];
        float psum = (t4[0] + t4[1]) + (t4[2] + t4[3]);
        psum = xsum64(psum);
        lsum += psum;

        #pragma unroll
        for (int s = 0; s < 4; ++s){
          const int sb = s >> 1, s1 = s & 1;
          unsigned u0 = cvtpk(S[sb][8 * s1 + 0], S[sb][8 * s1 + 1]);
          unsigned u1 = cvtpk(S[sb][8 * s1 + 2], S[sb][8 * s1 + 3]);
          unsigned u2 = cvtpk(S[sb][8 * s1 + 4], S[sb][8 * s1 + 5]);
          unsigned u3 = cvtpk(S[sb][8 * s1 + 6], S[sb][8 * s1 + 7]);
          permswap(u0, u2);
          permswap(u1, u3);
          union { unsigned u[4]; short8 s8; } pb;
          pb.u[0] = u0; pb.u[1] = u1; pb.u[2] = u2; pb.u[3] = u3;

          int col = 32 * s + 16 * hi;
          int r0 = lq, r1 = 32 + lq;
          short8 v0 = *(const short8*)(Vb + ((r0 * 128 + col) ^ ((r0 & 7) << 4)));
          short8 v1 = *(const short8*)(Vb + ((r1 * 128 + col) ^ ((r1 & 7) << 4)));
          Ot[0] = __builtin_amdgcn_mfma_f32_32x32x16_bf16(v0, pb.s8, Ot[0], 0, 0, 0);
          Ot[1] = __builtin_amdgcn_mfma_f32_32x32x16_bf16(v1, pb.s8, Ot[1], 0, 0, 0);
        }
      }
      __syncthreads();
    }

    float inv = 1.0f / lsum;
    unsigned short* ep = &ldsK[0][0] + wid * 2048;
    #pragma unroll
    for (int d = 0; d < 2; ++d)
      #pragma unroll
      for (int g = 0; g < 4; ++g)
        #pragma unroll
        for (int cp = 0; cp < 2; ++cp){
          int r = g * 4 + cp * 2;
          unsigned w = cvtpk(Ot[d][r] * inv, Ot[d][r + 1] * inv);
          int dd = d * 32 + g * 8 + 4 * hi + cp * 2;
          int byte = lq * 128 + ((dd * 2) ^ ((lq & 7) << 4));
          *(unsigned*)((char*)ep + byte) = w;
        }
    __syncthreads();
    #pragma unroll
    for (int i = 0; i < 4; ++i){
      int qr = i * 8 + (lane >> 3);
      int cc = lane & 7;
      int byte = qr * 128 + ((cc * 16) ^ ((qr & 7) << 4));
      short8 vv = *(const short8*)((const char*)ep + byte);
      *(short8*)(Att + ((size_t)(b * Ssz + q0w + qr)) * Dsz + hh * 64 + cc * 8) = vv;
    }
    __syncthreads();
  }
}

extern "C" void kernel_launch(void* const* d_in, const int* in_sizes, int n_in,
                              void* d_out, int out_size, void* d_ws, size_t ws_size,
                              hipStream_t stream) {
  const float* x    = (const float*)d_in[0];
  const float* Wqkv = (const float*)d_in[1];
  const float* bqkv = (const float*)d_in[2];
  const float* Wout = (const float*)d_in[3];
  const float* bout = (const float*)d_in[4];
  float* out = (float*)d_out;

  unsigned short* xb    = (unsigned short*)d_ws;                 // 8192*1024
  unsigned short* wqkvT = xb    + (size_t)8192 * 1024;           // 3072*1024
  unsigned short* woutT = wqkvT + (size_t)3072 * 1024;           // 1024*1024
  unsigned short* Qb    = woutT + (size_t)1024 * 1024;           // [B,H,S,HD]
  unsigned short* Kb    = Qb    + (size_t)8388608;
  unsigned short* Vtb   = Kb    + (size_t)8388608;
  unsigned short* Attb  = Vtb   + (size_t)8388608;

  cvt_kernel<<<4096, 256, 0, stream>>>(x, xb, 8388608);
  transpose_kernel<<<dim3(96, 32), dim3(32, 8), 0, stream>>>(Wqkv, wqkvT, 1024, 3072);
  transpose_kernel<<<dim3(32, 32), dim3(32, 8), 0, stream>>>(Wout, woutT, 1024, 1024);
  gemm_qkv<<<384, 512, 0, stream>>>(xb, wqkvT, bqkv, Qb, Kb, Vtb);
  attn_kernel<<<dim3(8, 64), 256, 0, stream>>>(Qb, Kb, Vtb, Attb);
  gemm_bt<<<dim3(8, 64), 256, 0, stream>>>(Attb, woutT, 8192, 1024, 1024, bout, out);
}

// Round 7
// 200.174 us; speedup vs baseline: 1.0524x; 1.0524x over previous
//
#include <hip/hip_runtime.h>
#include <hip/hip_bf16.h>

typedef __attribute__((ext_vector_type(4))) float f32x4;
typedef __attribute__((ext_vector_type(16))) float f32x16;
typedef __attribute__((ext_vector_type(8))) short short8;

static constexpr int Ssz = 2048;
static constexpr int Dsz = 1024;

__device__ __forceinline__ unsigned short f2bf(float f){
  union { float f; unsigned u; } c; c.f = f;
  unsigned r = c.u + 0x7fffu + ((c.u >> 16) & 1u);
  return (unsigned short)(r >> 16);
}

__device__ __forceinline__ void gl2lds16(const void* g, void* l){
  __builtin_amdgcn_global_load_lds(
    (const __attribute__((address_space(1))) unsigned int*)g,
    (__attribute__((address_space(3))) unsigned int*)l, 16, 0, 0);
}

__device__ __forceinline__ unsigned cvtpk(float lo, float hi){
  unsigned r;
  asm("v_cvt_pk_bf16_f32 %0, %1, %2" : "=v"(r) : "v"(lo), "v"(hi));
  return r;
}

__device__ __forceinline__ void permswap(unsigned &a, unsigned &b){
  asm volatile("v_permlane32_swap_b32 %0, %1" : "+v"(a), "+v"(b));
}

__device__ __forceinline__ float xmax64(float x){
  float a = x, b;
  asm volatile("v_mov_b32 %0, %1" : "=v"(b) : "v"(a));
  asm volatile("v_permlane32_swap_b32 %0, %1" : "+v"(a), "+v"(b));
  return fmaxf(a, b);
}
__device__ __forceinline__ float xsum64(float x){
  float a = x, b;
  asm volatile("v_mov_b32 %0, %1" : "=v"(b) : "v"(a));
  asm volatile("v_permlane32_swap_b32 %0, %1" : "+v"(a), "+v"(b));
  return a + b;
}

// ---------------- fp32 -> bf16 elementwise (8/thread) ----------------
__global__ void cvt_kernel(const float* __restrict__ in, unsigned short* __restrict__ out, int n){
  int i = (blockIdx.x * 256 + threadIdx.x) * 8;
  if (i >= n) return;
  float4 a = *(const float4*)(in + i);
  float4 b = *(const float4*)(in + i + 4);
  short8 o;
  o[0]=(short)f2bf(a.x); o[1]=(short)f2bf(a.y); o[2]=(short)f2bf(a.z); o[3]=(short)f2bf(a.w);
  o[4]=(short)f2bf(b.x); o[5]=(short)f2bf(b.y); o[6]=(short)f2bf(b.z); o[7]=(short)f2bf(b.w);
  *(short8*)(out + i) = o;
}

// ---------------- fp32 [R][C] -> bf16 [C][R] transpose ----------------
__global__ void transpose_kernel(const float* __restrict__ in, unsigned short* __restrict__ out,
                                 int R, int C){
  __shared__ float tile[32][33];
  int c0 = blockIdx.x * 32, r0 = blockIdx.y * 32;
  int tx = threadIdx.x, ty = threadIdx.y;
  #pragma unroll
  for (int k = 0; k < 4; ++k)
    tile[ty + 8*k][tx] = in[(size_t)(r0 + ty + 8*k) * C + c0 + tx];
  __syncthreads();
  #pragma unroll
  for (int k = 0; k < 4; ++k)
    out[(size_t)(c0 + ty + 8*k) * R + r0 + tx] = f2bf(tile[tx][ty + 8*k]);
}

// ---------------- bf16 GEMM: C[M][N] = A[M][K] * Bt[N][K]^T + bias ----------------
// mode 0: scatter to Q (exp2-prescaled), K, Vt. mode 1: fp32 out. (R3-proven, 80.5us)
#define BM 128
#define BN 128
#define BKg 64

__global__ __launch_bounds__(256, 2)
void gemm_bt(const unsigned short* __restrict__ A, const unsigned short* __restrict__ Bt,
             int M, int N, int K,
             const float* __restrict__ bias, int mode,
             unsigned short* __restrict__ Qp, unsigned short* __restrict__ Kp,
             unsigned short* __restrict__ Vtp, float* __restrict__ Out)
{
  __shared__ unsigned short ldsA[BM * BKg];
  __shared__ unsigned short ldsB[BN * BKg];
  const int tid = threadIdx.x;
  const int wid = tid >> 6;
  const int lane = tid & 63;
  const int lr = lane & 15, lg = lane >> 4;
  const int wr = wid >> 1, wc = wid & 1;
  const int m0 = blockIdx.y * BM, n0 = blockIdx.x * BN;

  const f32x4 vzero = {0.f, 0.f, 0.f, 0.f};
  f32x4 acc[4][4];
  #pragma unroll
  for (int i = 0; i < 4; ++i)
    #pragma unroll
    for (int j = 0; j < 4; ++j) acc[i][j] = vzero;

  for (int k0 = 0; k0 < K; k0 += BKg){
    __syncthreads();
    #pragma unroll
    for (int it = 0; it < 4; ++it){
      int c = it * 256 + tid;
      int row = c >> 3;
      int sc = (c & 7) ^ (row & 7);
      gl2lds16(A  + (size_t)(m0 + row) * K + k0 + sc * 8,
               (char*)ldsA + (it * 256 + wid * 64) * 16);
      gl2lds16(Bt + (size_t)(n0 + row) * K + k0 + sc * 8,
               (char*)ldsB + (it * 256 + wid * 64) * 16);
    }
    __syncthreads();
    #pragma unroll
    for (int kc = 0; kc < 2; ++kc){
      short8 af[4], bfr[4];
      #pragma unroll
      for (int i = 0; i < 4; ++i){
        int row = wr * 64 + i * 16 + lr;
        int off = row * 128 + lg * 16 + kc * 64;
        off ^= (row & 7) << 4;
        af[i] = *(const short8*)((const char*)ldsA + off);
      }
      #pragma unroll
      for (int j = 0; j < 4; ++j){
        int row = wc * 64 + j * 16 + lr;
        int off = row * 128 + lg * 16 + kc * 64;
        off ^= (row & 7) << 4;
        bfr[j] = *(const short8*)((const char*)ldsB + off);
      }
      #pragma unroll
      for (int i = 0; i < 4; ++i)
        #pragma unroll
        for (int j = 0; j < 4; ++j)
          acc[i][j] = __builtin_amdgcn_mfma_f32_16x16x32_bf16(af[i], bfr[j], acc[i][j], 0, 0, 0);
    }
  }

  if (mode == 0){
    // Q pre-scaled by 1/sqrt(HD) * log2(e): attention works in exp2 domain
    const float qscale = 0.125f * 1.4426950408889634f;
    #pragma unroll
    for (int i = 0; i < 4; ++i)
      #pragma unroll
      for (int j = 0; j < 4; ++j)
        #pragma unroll
        for (int r = 0; r < 4; ++r){
          int gm = m0 + wr * 64 + i * 16 + lg * 4 + r;
          int gn = n0 + wc * 64 + j * 16 + lr;
          float v = acc[i][j][r] + bias[gn];
          int which = gn >> 10;
          int h = (gn >> 6) & 15;
          int hd = gn & 63;
          int b = gm >> 11;
          int s = gm & 2047;
          size_t bh = (size_t)(b * 16 + h);
          if (which == 0)      Qp[(bh * Ssz + s) * 64 + hd] = f2bf(v * qscale);
          else if (which == 1) Kp[(bh * Ssz + s) * 64 + hd] = f2bf(v);
          else                 Vtp[(bh * 64 + hd) * Ssz + s] = f2bf(v);
        }
  } else {
    #pragma unroll
    for (int i = 0; i < 4; ++i)
      #pragma unroll
      for (int j = 0; j < 4; ++j)
        #pragma unroll
        for (int r = 0; r < 4; ++r){
          int gm = m0 + wr * 64 + i * 16 + lg * 4 + r;
          int gn = n0 + wc * 64 + j * 16 + lr;
          Out[(size_t)gm * N + gn] = acc[i][j][r] + bias[gn];
        }
  }
}

// ---------------- causal flash attention, swapped-QK 32x32 ----------------
// QBLK=64, 2-wave (128-thread) blocks; grid (16, B*H); block bx pairs q-tiles
// (bx, 31-bx) => exactly 33 K-tile units each; 1024 blocks = 4 independent
// blocks/CU (LDS 32KB each) for block-level latency hiding.
__global__ __launch_bounds__(128, 2)
void attn_kernel(const unsigned short* __restrict__ Qp, const unsigned short* __restrict__ Kp,
                 const unsigned short* __restrict__ Vtp, unsigned short* __restrict__ Att)
{
  __shared__ unsigned short ldsK[2][4096];
  __shared__ unsigned short ldsV[2][4096];
  const int tid = threadIdx.x;
  const int wid = tid >> 6;        // 0..1
  const int lane = tid & 63;
  const int lq = lane & 31;        // this lane's query column
  const int hi = lane >> 5;
  const int bh = blockIdx.y;
  const int b = bh >> 4, hh = bh & 15;

  #pragma unroll 1
  for (int job = 0; job < 2; ++job){
    const int qt = job ? (31 - (int)blockIdx.x) : (int)blockIdx.x;
    const int q0w = qt * 64 + wid * 32;
    const int qa = q0w + lq;
    const int nt = qt + 1;

    // Q B-fragments: lane holds Q[q0w+lq][ks*16 + 8*hi + j] (prescaled, log2e folded)
    short8 qf[4];
    {
      const unsigned short* Qb = Qp + ((size_t)bh * Ssz + q0w + lq) * 64 + hi * 8;
      #pragma unroll
      for (int ks = 0; ks < 4; ++ks) qf[ks] = *(const short8*)(Qb + ks * 16);
    }

    f32x16 Ot[2];
    #pragma unroll
    for (int d = 0; d < 2; ++d)
      #pragma unroll
      for (int r = 0; r < 16; ++r) Ot[d][r] = 0.f;
    float mrun = -3e38f, lsum = 0.f;

    // prologue: stage tile 0 into buf 0 (4 gl2lds K + 4 gl2lds V per thread)
    #pragma unroll
    for (int it = 0; it < 4; ++it){
      int c = it * 128 + tid;
      int row = c >> 3, sc = (c & 7) ^ (row & 7);
      gl2lds16(Kp  + ((size_t)bh * Ssz + row) * 64 + sc * 8,
               (char*)&ldsK[0][0] + c * 16);
      gl2lds16(Vtp + ((size_t)bh * 64 + row) * Ssz + sc * 8,
               (char*)&ldsV[0][0] + c * 16);
    }
    __syncthreads();

    for (int kt = 0; kt < nt; ++kt){
      const int cur = kt & 1;
      if (kt + 1 < nt){
        const int nxt = cur ^ 1;
        #pragma unroll
        for (int it = 0; it < 4; ++it){
          int c = it * 128 + tid;
          int row = c >> 3, sc = (c & 7) ^ (row & 7);
          gl2lds16(Kp  + ((size_t)bh * Ssz + (kt + 1) * 64 + row) * 64 + sc * 8,
                   (char*)&ldsK[nxt][0] + c * 16);
          gl2lds16(Vtp + ((size_t)bh * 64 + row) * Ssz + (kt + 1) * 64 + sc * 8,
                   (char*)&ldsV[nxt][0] + c * 16);
        }
      }

      {
        const char* Kb = (const char*)&ldsK[cur][0];
        const char* Vb = (const char*)&ldsV[cur][0];

        // S^T = K · Q^T : S[kb] covers keys kb*32..+31 (row = key, col = q)
        f32x16 S[2];
        #pragma unroll
        for (int kb = 0; kb < 2; ++kb)
          #pragma unroll
          for (int r = 0; r < 16; ++r) S[kb][r] = 0.f;
        #pragma unroll
        for (int ks = 0; ks < 4; ++ks){
          int col = 32 * ks + 16 * hi;
          int r0 = lq, r1 = 32 + lq;
          short8 k0 = *(const short8*)(Kb + ((r0 * 128 + col) ^ ((r0 & 7) << 4)));
          short8 k1 = *(const short8*)(Kb + ((r1 * 128 + col) ^ ((r1 & 7) << 4)));
          S[0] = __builtin_amdgcn_mfma_f32_32x32x16_bf16(k0, qf[ks], S[0], 0, 0, 0);
          S[1] = __builtin_amdgcn_mfma_f32_32x32x16_bf16(k1, qf[ks], S[1], 0, 0, 0);
        }

        // causal mask: key = kt*64 + kb*32 + (r&3) + 8*(r>>2) + 4*hi
        if (kt * 64 + 63 > q0w){
          #pragma unroll
          for (int r = 0; r < 16; ++r){
            int keyb = kt * 64 + (r & 3) + ((r >> 2) << 3) + 4 * hi;
            if (keyb > qa)      S[0][r] = -3e38f;
            if (keyb + 32 > qa) S[1][r] = -3e38f;
          }
        }

        // row max: in-register tree + cross-half combine
        float t16[16];
        #pragma unroll
        for (int r = 0; r < 16; ++r) t16[r] = fmaxf(S[0][r], S[1][r]);
        float t8[8];
        #pragma unroll
        for (int r = 0; r < 8; ++r) t8[r] = fmaxf(t16[r], t16[r + 8]);
        float t4[4];
        #pragma unroll
        for (int r = 0; r < 4; ++r) t4[r] = fmaxf(t8[r], t8[r + 4]);
        float pmax = fmaxf(fmaxf(t4[0], t4[1]), fmaxf(t4[2], t4[3]));
        pmax = xmax64(pmax);

        // defer-max (T13): skip O-rescale while tile max stays within 2^8
        if (!__all(pmax - mrun <= 8.0f)){
          float mn = fmaxf(mrun, pmax);
          float scl = __builtin_amdgcn_exp2f(mrun - mn);
          mrun = mn;
          lsum *= scl;
          #pragma unroll
          for (int d = 0; d < 2; ++d)
            #pragma unroll
            for (int r = 0; r < 16; ++r) Ot[d][r] *= scl;
        }

        #pragma unroll
        for (int kb = 0; kb < 2; ++kb)
          #pragma unroll
          for (int r = 0; r < 16; ++r)
            S[kb][r] = __builtin_amdgcn_exp2f(S[kb][r] - mrun);

        #pragma unroll
        for (int r = 0; r < 16; ++r) t16[r] = S[0][r] + S[1][r];
        #pragma unroll
        for (int r = 0; r < 8; ++r) t8[r] = t16[r] + t16[r + 8];
        #pragma unroll
        for (int r = 0; r < 4; ++r) t4[r] = t8[r] + t8[r + 4];
        float psum = (t4[0] + t4[1]) + (t4[2] + t4[3]);
        psum = xsum64(psum);
        lsum += psum;

        // PV: O^T[d][q] += V^T[d][key] * P^T[key][q]
        #pragma unroll
        for (int s = 0; s < 4; ++s){
          const int sb = s >> 1, s1 = s & 1;
          unsigned u0 = cvtpk(S[sb][8 * s1 + 0], S[sb][8 * s1 + 1]);
          unsigned u1 = cvtpk(S[sb][8 * s1 + 2], S[sb][8 * s1 + 3]);
          unsigned u2 = cvtpk(S[sb][8 * s1 + 4], S[sb][8 * s1 + 5]);
          unsigned u3 = cvtpk(S[sb][8 * s1 + 6], S[sb][8 * s1 + 7]);
          permswap(u0, u2);
          permswap(u1, u3);
          union { unsigned u[4]; short8 s8; } pb;
          pb.u[0] = u0; pb.u[1] = u1; pb.u[2] = u2; pb.u[3] = u3;

          int col = 32 * s + 16 * hi;
          int r0 = lq, r1 = 32 + lq;
          short8 v0 = *(const short8*)(Vb + ((r0 * 128 + col) ^ ((r0 & 7) << 4)));
          short8 v1 = *(const short8*)(Vb + ((r1 * 128 + col) ^ ((r1 & 7) << 4)));
          Ot[0] = __builtin_amdgcn_mfma_f32_32x32x16_bf16(v0, pb.s8, Ot[0], 0, 0, 0);
          Ot[1] = __builtin_amdgcn_mfma_f32_32x32x16_bf16(v1, pb.s8, Ot[1], 0, 0, 0);
        }
      }
      __syncthreads();
    }

    // epilogue: O^T/lsum -> per-wave swizzled LDS transpose -> coalesced stores
    float inv = 1.0f / lsum;
    unsigned short* ep = &ldsK[0][0] + wid * 2048;   // 4KB per wave
    #pragma unroll
    for (int d = 0; d < 2; ++d)
      #pragma unroll
      for (int g = 0; g < 4; ++g)
        #pragma unroll
        for (int cp = 0; cp < 2; ++cp){
          int r = g * 4 + cp * 2;
          unsigned w = cvtpk(Ot[d][r] * inv, Ot[d][r + 1] * inv);
          int dd = d * 32 + g * 8 + 4 * hi + cp * 2;
          int byte = lq * 128 + ((dd * 2) ^ ((lq & 7) << 4));
          *(unsigned*)((char*)ep + byte) = w;
        }
    __syncthreads();
    #pragma unroll
    for (int i = 0; i < 4; ++i){
      int qr = i * 8 + (lane >> 3);
      int cc = lane & 7;
      int byte = qr * 128 + ((cc * 16) ^ ((qr & 7) << 4));
      short8 vv = *(const short8*)((const char*)ep + byte);
      // ep holds THIS wave's rows; global base is q0w (already includes wid*32)
      *(short8*)(Att + ((size_t)(b * Ssz + q0w + qr)) * Dsz + hh * 64 + cc * 8) = vv;
    }
    __syncthreads();   // protect epilogue scratch before next job's staging
  }
}

extern "C" void kernel_launch(void* const* d_in, const int* in_sizes, int n_in,
                              void* d_out, int out_size, void* d_ws, size_t ws_size,
                              hipStream_t stream) {
  const float* x    = (const float*)d_in[0];
  const float* Wqkv = (const float*)d_in[1];
  const float* bqkv = (const float*)d_in[2];
  const float* Wout = (const float*)d_in[3];
  const float* bout = (const float*)d_in[4];
  float* out = (float*)d_out;

  unsigned short* xb    = (unsigned short*)d_ws;                 // 8192*1024
  unsigned short* wqkvT = xb    + (size_t)8192 * 1024;           // 3072*1024
  unsigned short* woutT = wqkvT + (size_t)3072 * 1024;           // 1024*1024
  unsigned short* Qb    = woutT + (size_t)1024 * 1024;           // [B,H,S,HD]
  unsigned short* Kb    = Qb    + (size_t)8388608;
  unsigned short* Vtb   = Kb    + (size_t)8388608;
  unsigned short* Attb  = Vtb   + (size_t)8388608;

  cvt_kernel<<<4096, 256, 0, stream>>>(x, xb, 8388608);
  transpose_kernel<<<dim3(96, 32), dim3(32, 8), 0, stream>>>(Wqkv, wqkvT, 1024, 3072);
  transpose_kernel<<<dim3(32, 32), dim3(32, 8), 0, stream>>>(Wout, woutT, 1024, 1024);
  gemm_bt<<<dim3(24, 64), 256, 0, stream>>>(xb, wqkvT, 8192, 3072, 1024,
                                            bqkv, 0, Qb, Kb, Vtb, nullptr);
  attn_kernel<<<dim3(16, 64), 128, 0, stream>>>(Qb, Kb, Vtb, Attb);
  gemm_bt<<<dim3(8, 64), 256, 0, stream>>>(Attb, woutT, 8192, 1024, 1024,
                                           bout, 1, nullptr, nullptr, nullptr, out);
}

// Round 8
// 178.726 us; speedup vs baseline: 1.1787x; 1.1200x over previous
//
#include <hip/hip_runtime.h>
#include <hip/hip_bf16.h>

typedef __attribute__((ext_vector_type(4))) float f32x4;
typedef __attribute__((ext_vector_type(16))) float f32x16;
typedef __attribute__((ext_vector_type(8))) short short8;

static constexpr int Ssz = 2048;
static constexpr int Dsz = 1024;

__device__ __forceinline__ unsigned short f2bf(float f){
  union { float f; unsigned u; } c; c.f = f;
  unsigned r = c.u + 0x7fffu + ((c.u >> 16) & 1u);
  return (unsigned short)(r >> 16);
}

__device__ __forceinline__ void gl2lds16(const void* g, void* l){
  __builtin_amdgcn_global_load_lds(
    (const __attribute__((address_space(1))) unsigned int*)g,
    (__attribute__((address_space(3))) unsigned int*)l, 16, 0, 0);
}

__device__ __forceinline__ unsigned cvtpk(float lo, float hi){
  unsigned r;
  asm("v_cvt_pk_bf16_f32 %0, %1, %2" : "=v"(r) : "v"(lo), "v"(hi));
  return r;
}

__device__ __forceinline__ void permswap(unsigned &a, unsigned &b){
  asm volatile("v_permlane32_swap_b32 %0, %1" : "+v"(a), "+v"(b));
}

__device__ __forceinline__ float xmax64(float x){
  float a = x, b;
  asm volatile("v_mov_b32 %0, %1" : "=v"(b) : "v"(a));
  asm volatile("v_permlane32_swap_b32 %0, %1" : "+v"(a), "+v"(b));
  return fmaxf(a, b);
}
__device__ __forceinline__ float xsum64(float x){
  float a = x, b;
  asm volatile("v_mov_b32 %0, %1" : "=v"(b) : "v"(a));
  asm volatile("v_permlane32_swap_b32 %0, %1" : "+v"(a), "+v"(b));
  return a + b;
}

// ---------------- fp32 -> bf16 elementwise (8/thread) ----------------
__global__ void cvt_kernel(const float* __restrict__ in, unsigned short* __restrict__ out, int n){
  int i = (blockIdx.x * 256 + threadIdx.x) * 8;
  if (i >= n) return;
  float4 a = *(const float4*)(in + i);
  float4 b = *(const float4*)(in + i + 4);
  short8 o;
  o[0]=(short)f2bf(a.x); o[1]=(short)f2bf(a.y); o[2]=(short)f2bf(a.z); o[3]=(short)f2bf(a.w);
  o[4]=(short)f2bf(b.x); o[5]=(short)f2bf(b.y); o[6]=(short)f2bf(b.z); o[7]=(short)f2bf(b.w);
  *(short8*)(out + i) = o;
}

// ---------------- fp32 [R][C] -> bf16 [C][R] transpose ----------------
__global__ void transpose_kernel(const float* __restrict__ in, unsigned short* __restrict__ out,
                                 int R, int C){
  __shared__ float tile[32][33];
  int c0 = blockIdx.x * 32, r0 = blockIdx.y * 32;
  int tx = threadIdx.x, ty = threadIdx.y;
  #pragma unroll
  for (int k = 0; k < 4; ++k)
    tile[ty + 8*k][tx] = in[(size_t)(r0 + ty + 8*k) * C + c0 + tx];
  __syncthreads();
  #pragma unroll
  for (int k = 0; k < 4; ++k)
    out[(size_t)(c0 + ty + 8*k) * R + r0 + tx] = f2bf(tile[tx][ty + 8*k]);
}

// ---------------- bf16 GEMM: C[M][N] = A[M][K] * Bt[N][K]^T + bias ----------------
// mode 0: scatter to Q (exp2-prescaled), K, Vt. mode 1: fp32 out. (R3-proven, 80.5us)
#define BM 128
#define BN 128
#define BKg 64

__global__ __launch_bounds__(256, 2)
void gemm_bt(const unsigned short* __restrict__ A, const unsigned short* __restrict__ Bt,
             int M, int N, int K,
             const float* __restrict__ bias, int mode,
             unsigned short* __restrict__ Qp, unsigned short* __restrict__ Kp,
             unsigned short* __restrict__ Vtp, float* __restrict__ Out)
{
  __shared__ unsigned short ldsA[BM * BKg];
  __shared__ unsigned short ldsB[BN * BKg];
  const int tid = threadIdx.x;
  const int wid = tid >> 6;
  const int lane = tid & 63;
  const int lr = lane & 15, lg = lane >> 4;
  const int wr = wid >> 1, wc = wid & 1;
  const int m0 = blockIdx.y * BM, n0 = blockIdx.x * BN;

  const f32x4 vzero = {0.f, 0.f, 0.f, 0.f};
  f32x4 acc[4][4];
  #pragma unroll
  for (int i = 0; i < 4; ++i)
    #pragma unroll
    for (int j = 0; j < 4; ++j) acc[i][j] = vzero;

  for (int k0 = 0; k0 < K; k0 += BKg){
    __syncthreads();
    #pragma unroll
    for (int it = 0; it < 4; ++it){
      int c = it * 256 + tid;
      int row = c >> 3;
      int sc = (c & 7) ^ (row & 7);
      gl2lds16(A  + (size_t)(m0 + row) * K + k0 + sc * 8,
               (char*)ldsA + (it * 256 + wid * 64) * 16);
      gl2lds16(Bt + (size_t)(n0 + row) * K + k0 + sc * 8,
               (char*)ldsB + (it * 256 + wid * 64) * 16);
    }
    __syncthreads();
    #pragma unroll
    for (int kc = 0; kc < 2; ++kc){
      short8 af[4], bfr[4];
      #pragma unroll
      for (int i = 0; i < 4; ++i){
        int row = wr * 64 + i * 16 + lr;
        int off = row * 128 + lg * 16 + kc * 64;
        off ^= (row & 7) << 4;
        af[i] = *(const short8*)((const char*)ldsA + off);
      }
      #pragma unroll
      for (int j = 0; j < 4; ++j){
        int row = wc * 64 + j * 16 + lr;
        int off = row * 128 + lg * 16 + kc * 64;
        off ^= (row & 7) << 4;
        bfr[j] = *(const short8*)((const char*)ldsB + off);
      }
      #pragma unroll
      for (int i = 0; i < 4; ++i)
        #pragma unroll
        for (int j = 0; j < 4; ++j)
          acc[i][j] = __builtin_amdgcn_mfma_f32_16x16x32_bf16(af[i], bfr[j], acc[i][j], 0, 0, 0);
    }
  }

  if (mode == 0){
    // Q pre-scaled by 1/sqrt(HD) * log2(e): attention works in exp2 domain
    const float qscale = 0.125f * 1.4426950408889634f;
    #pragma unroll
    for (int i = 0; i < 4; ++i)
      #pragma unroll
      for (int j = 0; j < 4; ++j)
        #pragma unroll
        for (int r = 0; r < 4; ++r){
          int gm = m0 + wr * 64 + i * 16 + lg * 4 + r;
          int gn = n0 + wc * 64 + j * 16 + lr;
          float v = acc[i][j][r] + bias[gn];
          int which = gn >> 10;
          int h = (gn >> 6) & 15;
          int hd = gn & 63;
          int b = gm >> 11;
          int s = gm & 2047;
          size_t bh = (size_t)(b * 16 + h);
          if (which == 0)      Qp[(bh * Ssz + s) * 64 + hd] = f2bf(v * qscale);
          else if (which == 1) Kp[(bh * Ssz + s) * 64 + hd] = f2bf(v);
          else                 Vtp[(bh * 64 + hd) * Ssz + s] = f2bf(v);
        }
  } else {
    #pragma unroll
    for (int i = 0; i < 4; ++i)
      #pragma unroll
      for (int j = 0; j < 4; ++j)
        #pragma unroll
        for (int r = 0; r < 4; ++r){
          int gm = m0 + wr * 64 + i * 16 + lg * 4 + r;
          int gn = n0 + wc * 64 + j * 16 + lr;
          Out[(size_t)gm * N + gn] = acc[i][j][r] + bias[gn];
        }
  }
}

// ---------------- causal flash attention, swapped-QK 32x32, balanced + XCD-local ----------------
// grid (8,64) = 512 blocks; flat id remapped so each XCD owns 8 heads (bh) =
// 4MB K/V = its whole L2. Within an XCD, 8 q-tile-pair blocks per bh.
// Block handles q-tiles (qx, 15-qx) of its bh => 34 equal K-tile units.
__global__ __launch_bounds__(256, 2)
void attn_kernel(const unsigned short* __restrict__ Qp, const unsigned short* __restrict__ Kp,
                 const unsigned short* __restrict__ Vtp, unsigned short* __restrict__ Att)
{
  __shared__ unsigned short ldsK[2][4096];
  __shared__ unsigned short ldsV[2][4096];
  const int tid = threadIdx.x;
  const int wid = tid >> 6;
  const int lane = tid & 63;
  const int lq = lane & 31;      // this lane's query column
  const int hi = lane >> 5;

  // XCD-aware remap: consecutive flat ids round-robin XCDs; give each XCD a
  // contiguous bh-group. flat = qx' + 8*bh' -> xcd = flat&7 owns bh in [xcd*8, xcd*8+8)
  const int flat = (int)blockIdx.x + 8 * (int)blockIdx.y;
  const int xcd = flat & 7;
  const int i6  = flat >> 3;           // 0..63
  const int bh  = xcd * 8 + (i6 >> 3); // 8 heads per XCD
  const int qx  = i6 & 7;              // q-tile-pair index
  const int b = bh >> 4, hh = bh & 15;

  #pragma unroll 1
  for (int job = 0; job < 2; ++job){
    const int qt = job ? (15 - qx) : qx;
    const int q0w = qt * 128 + wid * 32;
    const int qa = q0w + lq;
    const int nt = 2 * qt + 2;

    // Q B-fragments: lane holds Q[q0w+lq][ks*16 + 8*hi + j] (prescaled, log2e folded)
    short8 qf[4];
    {
      const unsigned short* Qb = Qp + ((size_t)bh * Ssz + q0w + lq) * 64 + hi * 8;
      #pragma unroll
      for (int ks = 0; ks < 4; ++ks) qf[ks] = *(const short8*)(Qb + ks * 16);
    }

    f32x16 Ot[2];
    #pragma unroll
    for (int d = 0; d < 2; ++d)
      #pragma unroll
      for (int r = 0; r < 16; ++r) Ot[d][r] = 0.f;
    float mrun = -3e38f, lsum = 0.f;

    // prologue: stage tile 0 into buf 0
    #pragma unroll
    for (int it = 0; it < 2; ++it){
      int c = it * 256 + tid;
      int row = c >> 3, sc = (c & 7) ^ (row & 7);
      gl2lds16(Kp  + ((size_t)bh * Ssz + row) * 64 + sc * 8,
               (char*)&ldsK[0][0] + (it * 256 + wid * 64) * 16);
      gl2lds16(Vtp + ((size_t)bh * 64 + row) * Ssz + sc * 8,
               (char*)&ldsV[0][0] + (it * 256 + wid * 64) * 16);
    }
    __syncthreads();

    for (int kt = 0; kt < nt; ++kt){
      const int cur = kt & 1;
      if (kt + 1 < nt){
        const int nxt = cur ^ 1;
        #pragma unroll
        for (int it = 0; it < 2; ++it){
          int c = it * 256 + tid;
          int row = c >> 3, sc = (c & 7) ^ (row & 7);
          gl2lds16(Kp  + ((size_t)bh * Ssz + (kt + 1) * 64 + row) * 64 + sc * 8,
                   (char*)&ldsK[nxt][0] + (it * 256 + wid * 64) * 16);
          gl2lds16(Vtp + ((size_t)bh * 64 + row) * Ssz + (kt + 1) * 64 + sc * 8,
                   (char*)&ldsV[nxt][0] + (it * 256 + wid * 64) * 16);
        }
      }

      if (kt * 64 <= q0w + 31){   // wave not fully masked for this tile
        const char* Kb = (const char*)&ldsK[cur][0];
        const char* Vb = (const char*)&ldsV[cur][0];

        // S^T = K · Q^T : S[kb] covers keys kb*32..+31 (row = key, col = q)
        f32x16 S[2];
        #pragma unroll
        for (int kb = 0; kb < 2; ++kb)
          #pragma unroll
          for (int r = 0; r < 16; ++r) S[kb][r] = 0.f;
        #pragma unroll
        for (int ks = 0; ks < 4; ++ks){
          int col = 32 * ks + 16 * hi;
          int r0 = lq, r1 = 32 + lq;
          short8 k0 = *(const short8*)(Kb + ((r0 * 128 + col) ^ ((r0 & 7) << 4)));
          short8 k1 = *(const short8*)(Kb + ((r1 * 128 + col) ^ ((r1 & 7) << 4)));
          S[0] = __builtin_amdgcn_mfma_f32_32x32x16_bf16(k0, qf[ks], S[0], 0, 0, 0);
          S[1] = __builtin_amdgcn_mfma_f32_32x32x16_bf16(k1, qf[ks], S[1], 0, 0, 0);
        }

        // causal mask: key = kt*64 + kb*32 + (r&3) + 8*(r>>2) + 4*hi
        if (kt * 64 + 63 > q0w){
          #pragma unroll
          for (int r = 0; r < 16; ++r){
            int keyb = kt * 64 + (r & 3) + ((r >> 2) << 3) + 4 * hi;
            if (keyb > qa)      S[0][r] = -3e38f;
            if (keyb + 32 > qa) S[1][r] = -3e38f;
          }
        }

        // row max: in-register tree + cross-half combine
        float t16[16];
        #pragma unroll
        for (int r = 0; r < 16; ++r) t16[r] = fmaxf(S[0][r], S[1][r]);
        float t8[8];
        #pragma unroll
        for (int r = 0; r < 8; ++r) t8[r] = fmaxf(t16[r], t16[r + 8]);
        float t4[4];
        #pragma unroll
        for (int r = 0; r < 4; ++r) t4[r] = fmaxf(t8[r], t8[r + 4]);
        float pmax = fmaxf(fmaxf(t4[0], t4[1]), fmaxf(t4[2], t4[3]));
        pmax = xmax64(pmax);

        // defer-max (T13): skip O-rescale while tile max stays within 2^8
        if (!__all(pmax - mrun <= 8.0f)){
          float mn = fmaxf(mrun, pmax);
          float scl = __builtin_amdgcn_exp2f(mrun - mn);
          mrun = mn;
          lsum *= scl;
          #pragma unroll
          for (int d = 0; d < 2; ++d)
            #pragma unroll
            for (int r = 0; r < 16; ++r) Ot[d][r] *= scl;
        }

        #pragma unroll
        for (int kb = 0; kb < 2; ++kb)
          #pragma unroll
          for (int r = 0; r < 16; ++r)
            S[kb][r] = __builtin_amdgcn_exp2f(S[kb][r] - mrun);

        #pragma unroll
        for (int r = 0; r < 16; ++r) t16[r] = S[0][r] + S[1][r];
        #pragma unroll
        for (int r = 0; r < 8; ++r) t8[r] = t16[r] + t16[r + 8];
        #pragma unroll
        for (int r = 0; r < 4; ++r) t4[r] = t8[r] + t8[r + 4];
        float psum = (t4[0] + t4[1]) + (t4[2] + t4[3]);
        psum = xsum64(psum);
        lsum += psum;

        // PV: O^T[d][q] += V^T[d][key] * P^T[key][q]
        #pragma unroll
        for (int s = 0; s < 4; ++s){
          const int sb = s >> 1, s1 = s & 1;
          unsigned u0 = cvtpk(S[sb][8 * s1 + 0], S[sb][8 * s1 + 1]);
          unsigned u1 = cvtpk(S[sb][8 * s1 + 2], S[sb][8 * s1 + 3]);
          unsigned u2 = cvtpk(S[sb][8 * s1 + 4], S[sb][8 * s1 + 5]);
          unsigned u3 = cvtpk(S[sb][8 * s1 + 6], S[sb][8 * s1 + 7]);
          permswap(u0, u2);
          permswap(u1, u3);
          union { unsigned u[4]; short8 s8; } pb;
          pb.u[0] = u0; pb.u[1] = u1; pb.u[2] = u2; pb.u[3] = u3;

          int col = 32 * s + 16 * hi;
          int r0 = lq, r1 = 32 + lq;
          short8 v0 = *(const short8*)(Vb + ((r0 * 128 + col) ^ ((r0 & 7) << 4)));
          short8 v1 = *(const short8*)(Vb + ((r1 * 128 + col) ^ ((r1 & 7) << 4)));
          Ot[0] = __builtin_amdgcn_mfma_f32_32x32x16_bf16(v0, pb.s8, Ot[0], 0, 0, 0);
          Ot[1] = __builtin_amdgcn_mfma_f32_32x32x16_bf16(v1, pb.s8, Ot[1], 0, 0, 0);
        }
      }
      __syncthreads();
    }

    // epilogue: O^T/lsum -> per-wave swizzled LDS transpose -> coalesced stores
    float inv = 1.0f / lsum;
    unsigned short* ep = &ldsK[0][0] + wid * 2048;   // 4KB per wave
    #pragma unroll
    for (int d = 0; d < 2; ++d)
      #pragma unroll
      for (int g = 0; g < 4; ++g)
        #pragma unroll
        for (int cp = 0; cp < 2; ++cp){
          int r = g * 4 + cp * 2;
          unsigned w = cvtpk(Ot[d][r] * inv, Ot[d][r + 1] * inv);
          int dd = d * 32 + g * 8 + 4 * hi + cp * 2;
          int byte = lq * 128 + ((dd * 2) ^ ((lq & 7) << 4));
          *(unsigned*)((char*)ep + byte) = w;
        }
    __syncthreads();
    #pragma unroll
    for (int ii = 0; ii < 4; ++ii){
      int qr = ii * 8 + (lane >> 3);
      int cc = lane & 7;
      int byte = qr * 128 + ((cc * 16) ^ ((qr & 7) << 4));
      short8 vv = *(const short8*)((const char*)ep + byte);
      *(short8*)(Att + ((size_t)(b * Ssz + q0w + qr)) * Dsz + hh * 64 + cc * 8) = vv;
    }
    __syncthreads();   // protect epilogue scratch before next job's staging
  }
}

extern "C" void kernel_launch(void* const* d_in, const int* in_sizes, int n_in,
                              void* d_out, int out_size, void* d_ws, size_t ws_size,
                              hipStream_t stream) {
  const float* x    = (const float*)d_in[0];
  const float* Wqkv = (const float*)d_in[1];
  const float* bqkv = (const float*)d_in[2];
  const float* Wout = (const float*)d_in[3];
  const float* bout = (const float*)d_in[4];
  float* out = (float*)d_out;

  unsigned short* xb    = (unsigned short*)d_ws;                 // 8192*1024
  unsigned short* wqkvT = xb    + (size_t)8192 * 1024;           // 3072*1024
  unsigned short* woutT = wqkvT + (size_t)3072 * 1024;           // 1024*1024
  unsigned short* Qb    = woutT + (size_t)1024 * 1024;           // [B,H,S,HD]
  unsigned short* Kb    = Qb    + (size_t)8388608;
  unsigned short* Vtb   = Kb    + (size_t)8388608;
  unsigned short* Attb  = Vtb   + (size_t)8388608;

  cvt_kernel<<<4096, 256, 0, stream>>>(x, xb, 8388608);
  transpose_kernel<<<dim3(96, 32), dim3(32, 8), 0, stream>>>(Wqkv, wqkvT, 1024, 3072);
  transpose_kernel<<<dim3(32, 32), dim3(32, 8), 0, stream>>>(Wout, woutT, 1024, 1024);
  gemm_bt<<<dim3(24, 64), 256, 0, stream>>>(xb, wqkvT, 8192, 3072, 1024,
                                            bqkv, 0, Qb, Kb, Vtb, nullptr);
  attn_kernel<<<dim3(8, 64), 256, 0, stream>>>(Qb, Kb, Vtb, Attb);
  gemm_bt<<<dim3(8, 64), 256, 0, stream>>>(Attb, woutT, 8192, 1024, 1024,
                                           bout, 1, nullptr, nullptr, nullptr, out);
}